// Round 1
// baseline (186.254 us; speedup 1.0000x reference)
//
#include <hip/hip_runtime.h>
#include <math.h>

#define Bsz 8192
#define Dd  128
#define BM  64                     // rows per main block
#define NSLICE 8                   // j-slices, keyed to XCD = blockIdx & 7
#define NRB (Bsz / BM)             // 128 row-blocks
#define ROT2(x) ((((x) << 2) | ((x) >> 4)) & 63)   // granule bank swizzle

typedef __attribute__((ext_vector_type(8))) short short8;   // 8 bf16 = 4 VGPR
typedef __attribute__((ext_vector_type(4))) float float4v;  // MFMA C/D frag

static constexpr float INV_T = 1.0f / 0.07f;  // logit scale; also fixed logsumexp shift
static constexpr float K1 =  20.60992915555662f;   // (1/T)*log2(e)
static constexpr float K2 = -20.60992915555662f;   // exp((S-1)/T) == exp2(S*K1 + K2)

// RNE float->bf16 pack (x -> low16, y -> high16)
static __device__ inline unsigned pack_bf16(float x, float y) {
    union { float f; unsigned u; } a, b;
    a.f = x; b.f = y;
    unsigned ra = a.u + 0x7FFF + ((a.u >> 16) & 1);
    unsigned rb = b.u + 0x7FFF + ((b.u >> 16) & 1);
    return (ra >> 16) | (rb & 0xFFFF0000u);
}

// ---------------- init: zero the packed compaction counter + done counters ----
__global__ void init_kernel(unsigned long long* __restrict__ cnt,
                            int* __restrict__ done) {
    const int t = threadIdx.x;
    if (t == 0) cnt[0] = 0ull;
    if (t < NRB) done[t] = 0;
}

// ---------------- prep: 32 rows/block, float4 loads, half-wave butterflies ----
// 1024 threads = 16 waves; wave w owns rows (2w, 2w+1): lane<32 -> row 2w, else 2w+1.
// Lane's c = lane&31 indexes the row's float4 chunk. ONE packed atomic per block.
__global__ __launch_bounds__(1024) void prep_kernel(
    const float4* __restrict__ fv4, const float4* __restrict__ fi4,
    const float4* __restrict__ v4,  const float4* __restrict__ vi4,
    unsigned* __restrict__ Xb, uint2* __restrict__ Yf0, uint2* __restrict__ Yf1,
    float* __restrict__ posArr, int* __restrict__ origArr, int* __restrict__ flagArr,
    float* __restrict__ lAcc, unsigned long long* __restrict__ cnt)
{
    __shared__ unsigned sT0[32 * 66];   // row stride 66 words (even: uint2-aligned)
    __shared__ unsigned sT1[32 * 66];
    __shared__ int sFlagL[32];
    __shared__ int sRank[32];
    __shared__ unsigned sBase[2];

    const int t    = threadIdx.x;
    const int wave = t >> 6;
    const int lane = t & 63;
    const int half = lane >> 5;
    const int c    = lane & 31;
    const int rl   = wave * 2 + half;          // row-local 0..31
    const int b    = blockIdx.x * 32 + rl;     // global row
    const int src  = b * 32 + c;               // float4 index into [B,128]

    const float4 afv = fv4[src];
    const float4 afi = fi4[src];
    const float4 av  = v4[src];
    const float4 avi = vi4[src];

    float nfv = afv.x*afv.x + afv.y*afv.y + afv.z*afv.z + afv.w*afv.w;
    float nfi = afi.x*afi.x + afi.y*afi.y + afi.z*afi.z + afi.w*afi.w;
    float nv  = av.x*av.x   + av.y*av.y   + av.z*av.z   + av.w*av.w;
    float nvi = avi.x*avi.x + avi.y*avi.y + avi.z*avi.z + avi.w*avi.w;
    float dv  = afv.x*av.x  + afv.y*av.y  + afv.z*av.z  + afv.w*av.w;
    float di  = afi.x*avi.x + afi.y*avi.y + afi.z*avi.z + afi.w*avi.w;

    #pragma unroll
    for (int m = 1; m < 32; m <<= 1) {   // half-wave butterfly (rows are 32-lane groups)
        nfv += __shfl_xor(nfv, m);
        nfi += __shfl_xor(nfi, m);
        nv  += __shfl_xor(nv,  m);
        nvi += __shfl_xor(nvi, m);
        dv  += __shfl_xor(dv,  m);
        di  += __shfl_xor(di,  m);
    }

    const float rnfv = 1.0f / fmaxf(sqrtf(nfv), 1e-12f);
    const float rnfi = 1.0f / fmaxf(sqrtf(nfi), 1e-12f);
    const float rnv  = 1.0f / fmaxf(sqrtf(nv ), 1e-12f);
    const float rnvi = 1.0f / fmaxf(sqrtf(nvi), 1e-12f);

    const float pos_v = dv * rnfv * rnv;
    const float pos_i = di * rnfi * rnvi;
    const bool useV = (pos_v >= pos_i);
    const float pos = useV ? pos_v : pos_i;

    // stage normalized Y rows as packed d-pair words for the fragment transpose
    uint2 w0y = make_uint2(pack_bf16(av.x  * rnv,  av.y  * rnv),
                           pack_bf16(av.z  * rnv,  av.w  * rnv));
    uint2 w1y = make_uint2(pack_bf16(avi.x * rnvi, avi.y * rnvi),
                           pack_bf16(avi.z * rnvi, avi.w * rnvi));
    *(uint2*)&sT0[rl * 66 + c * 2] = w0y;
    *(uint2*)&sT1[rl * 66 + c * 2] = w1y;
    if (c == 0) sFlagL[rl] = useV ? 0 : 1;
    __syncthreads();

    // wave 0: block-local ranks + ONE packed 64-bit atomic for both counters
    if (t < 64) {
        const int f = (lane < 32) ? sFlagL[lane] : 2;
        const unsigned long long m0 = __ballot(f == 0);
        const unsigned long long m1 = __ballot(f == 1);
        if (lane == 0) {
            const unsigned long long add =
                (unsigned long long)__popcll(m0) | ((unsigned long long)__popcll(m1) << 32);
            const unsigned long long ret = atomicAdd(cnt, add);
            sBase[0] = (unsigned)(ret & 0xffffffffull);
            sBase[1] = (unsigned)(ret >> 32);
        }
        if (lane < 32) {
            const unsigned long long below = (1ull << lane) - 1ull;
            sRank[lane] = (f == 0) ? (int)__popcll(m0 & below) : (int)__popcll(m1 & below);
        }
    }

    // fragment-ordered Yf write (independent of compaction; overlaps the atomic)
    // uint2 u = blk*1024 + t  <->  words o=2t: tl=t>>9, kc=(t>>7)&3, lp=(t>>1)&63, w0=(t&1)*2
    {
        const int tl = t >> 9;
        const int kc = (t >> 7) & 3;
        const int lp = (t >> 1) & 63;
        const int w0 = (t & 1) * 2;
        const int row = tl * 16 + (lp & 15);
        const int s   = kc * 16 + (lp >> 4) * 4 + w0;   // d-pair word within row
        Yf0[blockIdx.x * 1024 + t] = *(const uint2*)&sT0[row * 66 + s];
        Yf1[blockIdx.x * 1024 + t] = *(const uint2*)&sT1[row * 66 + s];
    }
    __syncthreads();

    const int f  = sFlagL[rl];
    const int rk = sRank[rl];
    const int p  = (f == 0) ? (int)(sBase[0] + rk) : (Bsz - 1 - (int)(sBase[1] + rk));

    const float sc = useV ? rnfv : rnfi;
    ((uint2*)Xb)[p * 32 + c] = make_uint2(pack_bf16(afv.x * sc, afv.y * sc),
                                          pack_bf16(afv.z * sc, afv.w * sc));
    // note: afv/afi selection
    if (!useV)
        ((uint2*)Xb)[p * 32 + c] = make_uint2(pack_bf16(afi.x * sc, afi.y * sc),
                                              pack_bf16(afi.z * sc, afi.w * sc));

    if (c == 0) {
        posArr[p]  = pos;
        origArr[p] = b;
        flagArr[p] = f;
        lAcc[p]    = 0.0f;
    }
}

// ---------------- main: BM=64, XCD-sliced, 4 blocks/CU, fused finish ----------
// grid 1024 1-D: slice = blk&7 (XCD-keyed j-range), rowblk = blk>>3.
// 4 waves: each owns ALL 64 rows (afr[4][4]) and 16 of the slice's 64 col-tiles.
// A/B frag: [m|n=lane&15][k=quad*8+j]; C/D: col=lane&15, row=quad*4+reg.
//
// Register budget (cap 128 @ 4 blocks/CU): afr 64 + rowsum 16 + acc 16 + b 16
// + misc ~8 = ~120.  No cross-tile prefetch: 4 waves/SIMD × ~240 issue-cyc/jt
// hide one wave's ~200-cyc L2 latency (TLP), so we spend the registers on NOT
// spilling instead.  Per-element exp-sum is unconditional (3 VALU insts:
// v_fma + v_exp + v_add); flavor predication moved to the once-per-phase
// reduce+atomic (at most ONE mixed-flavor block in the whole grid).
__global__ __launch_bounds__(256, 4) void main_kernel(
    const unsigned short* __restrict__ Xb,
    const uint4* __restrict__ Yf0q, const uint4* __restrict__ Yf1q,
    const int* __restrict__ flagArr, float* __restrict__ lAcc,
    const float* __restrict__ posArr, const int* __restrict__ origArr,
    int* __restrict__ done, float* __restrict__ out)
{
    __shared__ uint4 sXf[1024];        // 16 KB: X fragment-ordered, rot2-swizzled
    __shared__ int sFlag[BM];
    __shared__ int sHas[2];
    __shared__ int sLast;

    const int t    = threadIdx.x;
    const int wave = t >> 6;
    const int lane = t & 63;
    const int quad = lane >> 4;
    const int mrow = lane & 15;
    const int slice = blockIdx.x & 7;
    const int rb    = blockIdx.x >> 3;
    const int p0    = rb * BM;

    if (t < 2) sHas[t] = 0;
    __syncthreads();
    if (t < BM) {
        const int f = flagArr[p0 + t];
        sFlag[t] = f;
        atomicOr(&sHas[f], 1);
    }

    // stage X fragment-ordered with rot2 bank swizzle (conflict-free write+read)
    #pragma unroll
    for (int it = 0; it < 4; ++it) {
        const int i = t + it * 256;
        const int row = i >> 4, ch = i & 15;
        const uint4 val = ((const uint4*)Xb)[(p0 + row) * 16 + ch];
        const int blk16 = (row >> 4) * 4 + (ch >> 2);
        const int slot  = (ch & 3) * 16 + (row & 15);
        sXf[blk16 * 64 + ROT2(slot)] = val;
    }
    __syncthreads();

    // persistent A fragments (slot == lane identity => read at ROT2(lane))
    short8 afr[4][4];
    #pragma unroll
    for (int rt = 0; rt < 4; ++rt)
        #pragma unroll
        for (int kc = 0; kc < 4; ++kc)
            afr[rt][kc] = *(const short8*)&sXf[(rt * 4 + kc) * 64 + ROT2(lane)];

    const int g0 = slice * 64 + wave * 16;   // first of 16 col-tiles for this wave

    for (int phase = 0; phase < 2; ++phase) {
        if (!sHas[phase]) continue;          // flavor-pure blocks run one phase
        const uint4* __restrict__ yb = (phase ? Yf1q : Yf0q) + (size_t)g0 * 256 + lane;

        float rowsum[4][4] = {};             // unconditional per-phase exp-sums

        #pragma unroll 1
        for (int jt = 0; jt < 16; ++jt) {
            const short8 b0 = *(const short8*)&yb[0];      // tile g, kc0
            const short8 b1 = *(const short8*)&yb[64];     // kc1
            const short8 b2 = *(const short8*)&yb[128];    // kc2
            const short8 b3 = *(const short8*)&yb[192];    // kc3

            float4v acc[4] = {};
            #pragma unroll
            for (int rt = 0; rt < 4; ++rt)
                acc[rt] = __builtin_amdgcn_mfma_f32_16x16x32_bf16(afr[rt][0], b0, acc[rt], 0, 0, 0);
            #pragma unroll
            for (int rt = 0; rt < 4; ++rt)
                acc[rt] = __builtin_amdgcn_mfma_f32_16x16x32_bf16(afr[rt][1], b1, acc[rt], 0, 0, 0);
            #pragma unroll
            for (int rt = 0; rt < 4; ++rt)
                acc[rt] = __builtin_amdgcn_mfma_f32_16x16x32_bf16(afr[rt][2], b2, acc[rt], 0, 0, 0);
            #pragma unroll
            for (int rt = 0; rt < 4; ++rt)
                acc[rt] = __builtin_amdgcn_mfma_f32_16x16x32_bf16(afr[rt][3], b3, acc[rt], 0, 0, 0);

            // fused exp-sum: exp((S-1)/T) == exp2(S*K1 + K2)  -> v_fma + v_exp + v_add
            #pragma unroll
            for (int rt = 0; rt < 4; ++rt)
                #pragma unroll
                for (int r = 0; r < 4; ++r)
                    rowsum[rt][r] += exp2f(fmaf(acc[rt][r], K1, K2));

            yb += 256;
        }

        // reduce over the 16 col-lanes of each quad, then flag-predicated atomic
        #pragma unroll
        for (int m = 1; m < 16; m <<= 1)
            #pragma unroll
            for (int rt = 0; rt < 4; ++rt)
                #pragma unroll
                for (int r = 0; r < 4; ++r)
                    rowsum[rt][r] += __shfl_xor(rowsum[rt][r], m);

        if (mrow == 0) {
            #pragma unroll
            for (int rt = 0; rt < 4; ++rt)
                #pragma unroll
                for (int r = 0; r < 4; ++r) {
                    const int row = rt * 16 + quad * 4 + r;
                    if (sFlag[row] == phase)
                        atomicAdd(&lAcc[p0 + row], rowsum[rt][r]);
                }
        }
    }

    // ---- fused finish: last slice-block of this rowblock writes the loss ----
    __threadfence();                          // release our lAcc atomics
    __syncthreads();
    if (t == 0)
        sLast = (__hip_atomic_fetch_add(&done[rb], 1, __ATOMIC_ACQ_REL,
                                        __HIP_MEMORY_SCOPE_AGENT) == NSLICE - 1);
    __syncthreads();
    if (sLast && t < BM) {
        const int p = p0 + t;
        const float a = __hip_atomic_load(&lAcc[p], __ATOMIC_RELAXED,
                                          __HIP_MEMORY_SCOPE_AGENT);
        out[origArr[p]] = logf(a) + INV_T - posArr[p] * INV_T;
    }
}

// ---------------- launch ----------------
extern "C" void kernel_launch(void* const* d_in, const int* in_sizes, int n_in,
                              void* d_out, int out_size, void* d_ws, size_t ws_size,
                              hipStream_t stream)
{
    const float4* fv = (const float4*)d_in[0];
    const float4* fi = (const float4*)d_in[1];
    const float4* v  = (const float4*)d_in[2];
    const float4* vi = (const float4*)d_in[3];
    float* out = (float*)d_out;

    unsigned short* Xb  = (unsigned short*)d_ws;   // [B,128] bf16 row-major, compacted X
    unsigned short* Yf0 = Xb  + Bsz * Dd;          // [B*128] bf16, B-fragment-ordered v
    unsigned short* Yf1 = Yf0 + Bsz * Dd;          // [B*128] bf16, B-fragment-ordered vi
    float* posArr = (float*)(Yf1 + Bsz * Dd);      // [B] positive logit (compacted idx)
    float* lAcc   = posArr + Bsz;                  // [B] exp-sum accumulator
    int*  origArr = (int*)(lAcc + Bsz);            // [B] compacted -> original row
    int*  flagArr = origArr + Bsz;                 // [B] flavor per compacted row
    int*  done    = flagArr + Bsz;                 // [NRB] slice-completion counters
    unsigned long long* cnt = (unsigned long long*)(done + NRB);

    hipLaunchKernelGGL(init_kernel, dim3(1), dim3(128), 0, stream, cnt, done);
    hipLaunchKernelGGL(prep_kernel, dim3(Bsz / 32), dim3(1024), 0, stream,
                       fv, fi, v, vi, (unsigned*)Xb, (uint2*)Yf0, (uint2*)Yf1,
                       posArr, origArr, flagArr, lAcc, cnt);
    hipLaunchKernelGGL(main_kernel, dim3(NRB * NSLICE), dim3(256), 0, stream,
                       Xb, (const uint4*)Yf0, (const uint4*)Yf1, flagArr, lAcc,
                       posArr, origArr, done, out);
}

// Round 2
// 110.225 us; speedup vs baseline: 1.6898x; 1.6898x over previous
//
#include <hip/hip_runtime.h>
#include <math.h>

#define Bsz 8192
#define Dd  128
#define BM  64                     // rows per main block
#define NSLICE 8                   // j-slices, keyed to XCD = blockIdx & 7
#define ROT2(x) ((((x) << 2) | ((x) >> 4)) & 63)   // granule bank swizzle

typedef __attribute__((ext_vector_type(8))) short short8;   // 8 bf16 = 4 VGPR
typedef __attribute__((ext_vector_type(4))) float float4v;  // MFMA C/D frag

static constexpr float INV_T = 1.0f / 0.07f;  // logit scale; also fixed logsumexp shift
static constexpr float K1 =  20.60992915555662f;   // (1/T)*log2(e)
static constexpr float K2 = -20.60992915555662f;   // exp((S-1)/T) == exp2(S*K1 + K2)

// RNE float->bf16 pack (x -> low16, y -> high16)
static __device__ inline unsigned pack_bf16(float x, float y) {
    union { float f; unsigned u; } a, b;
    a.f = x; b.f = y;
    unsigned ra = a.u + 0x7FFF + ((a.u >> 16) & 1);
    unsigned rb = b.u + 0x7FFF + ((b.u >> 16) & 1);
    return (ra >> 16) | (rb & 0xFFFF0000u);
}

// ---------------- init: zero the packed compaction counter ----------------
__global__ void init_kernel(unsigned long long* __restrict__ cnt) {
    if (threadIdx.x == 0) cnt[0] = 0ull;
}

// ---------------- prep: 32 rows/block, float4 loads, half-wave butterflies ----
// 1024 threads = 16 waves; wave w owns rows (2w, 2w+1): lane<32 -> row 2w, else 2w+1.
// Lane's c = lane&31 indexes the row's float4 chunk. ONE packed atomic per block.
__global__ __launch_bounds__(1024) void prep_kernel(
    const float4* __restrict__ fv4, const float4* __restrict__ fi4,
    const float4* __restrict__ v4,  const float4* __restrict__ vi4,
    unsigned* __restrict__ Xb, uint2* __restrict__ Yf0, uint2* __restrict__ Yf1,
    float* __restrict__ posArr, int* __restrict__ origArr, int* __restrict__ flagArr,
    float* __restrict__ lAcc, unsigned long long* __restrict__ cnt)
{
    __shared__ unsigned sT0[32 * 66];   // row stride 66 words (even: uint2-aligned)
    __shared__ unsigned sT1[32 * 66];
    __shared__ int sFlagL[32];
    __shared__ int sRank[32];
    __shared__ unsigned sBase[2];

    const int t    = threadIdx.x;
    const int wave = t >> 6;
    const int lane = t & 63;
    const int half = lane >> 5;
    const int c    = lane & 31;
    const int rl   = wave * 2 + half;          // row-local 0..31
    const int b    = blockIdx.x * 32 + rl;     // global row
    const int src  = b * 32 + c;               // float4 index into [B,128]

    const float4 afv = fv4[src];
    const float4 afi = fi4[src];
    const float4 av  = v4[src];
    const float4 avi = vi4[src];

    float nfv = afv.x*afv.x + afv.y*afv.y + afv.z*afv.z + afv.w*afv.w;
    float nfi = afi.x*afi.x + afi.y*afi.y + afi.z*afi.z + afi.w*afi.w;
    float nv  = av.x*av.x   + av.y*av.y   + av.z*av.z   + av.w*av.w;
    float nvi = avi.x*avi.x + avi.y*avi.y + avi.z*avi.z + avi.w*avi.w;
    float dv  = afv.x*av.x  + afv.y*av.y  + afv.z*av.z  + afv.w*av.w;
    float di  = afi.x*avi.x + afi.y*avi.y + afi.z*avi.z + afi.w*avi.w;

    #pragma unroll
    for (int m = 1; m < 32; m <<= 1) {   // half-wave butterfly (rows are 32-lane groups)
        nfv += __shfl_xor(nfv, m);
        nfi += __shfl_xor(nfi, m);
        nv  += __shfl_xor(nv,  m);
        nvi += __shfl_xor(nvi, m);
        dv  += __shfl_xor(dv,  m);
        di  += __shfl_xor(di,  m);
    }

    const float rnfv = 1.0f / fmaxf(sqrtf(nfv), 1e-12f);
    const float rnfi = 1.0f / fmaxf(sqrtf(nfi), 1e-12f);
    const float rnv  = 1.0f / fmaxf(sqrtf(nv ), 1e-12f);
    const float rnvi = 1.0f / fmaxf(sqrtf(nvi), 1e-12f);

    const float pos_v = dv * rnfv * rnv;
    const float pos_i = di * rnfi * rnvi;
    const bool useV = (pos_v >= pos_i);
    const float pos = useV ? pos_v : pos_i;

    // stage normalized Y rows as packed d-pair words for the fragment transpose
    uint2 w0y = make_uint2(pack_bf16(av.x  * rnv,  av.y  * rnv),
                           pack_bf16(av.z  * rnv,  av.w  * rnv));
    uint2 w1y = make_uint2(pack_bf16(avi.x * rnvi, avi.y * rnvi),
                           pack_bf16(avi.z * rnvi, avi.w * rnvi));
    *(uint2*)&sT0[rl * 66 + c * 2] = w0y;
    *(uint2*)&sT1[rl * 66 + c * 2] = w1y;
    if (c == 0) sFlagL[rl] = useV ? 0 : 1;
    __syncthreads();

    // wave 0: block-local ranks + ONE packed 64-bit atomic for both counters
    if (t < 64) {
        const int f = (lane < 32) ? sFlagL[lane] : 2;
        const unsigned long long m0 = __ballot(f == 0);
        const unsigned long long m1 = __ballot(f == 1);
        if (lane == 0) {
            const unsigned long long add =
                (unsigned long long)__popcll(m0) | ((unsigned long long)__popcll(m1) << 32);
            const unsigned long long ret = atomicAdd(cnt, add);
            sBase[0] = (unsigned)(ret & 0xffffffffull);
            sBase[1] = (unsigned)(ret >> 32);
        }
        if (lane < 32) {
            const unsigned long long below = (1ull << lane) - 1ull;
            sRank[lane] = (f == 0) ? (int)__popcll(m0 & below) : (int)__popcll(m1 & below);
        }
    }

    // fragment-ordered Yf write (independent of compaction; overlaps the atomic)
    // uint2 u = blk*1024 + t  <->  words o=2t: tl=t>>9, kc=(t>>7)&3, lp=(t>>1)&63, w0=(t&1)*2
    {
        const int tl = t >> 9;
        const int kc = (t >> 7) & 3;
        const int lp = (t >> 1) & 63;
        const int w0 = (t & 1) * 2;
        const int row = tl * 16 + (lp & 15);
        const int s   = kc * 16 + (lp >> 4) * 4 + w0;   // d-pair word within row
        Yf0[blockIdx.x * 1024 + t] = *(const uint2*)&sT0[row * 66 + s];
        Yf1[blockIdx.x * 1024 + t] = *(const uint2*)&sT1[row * 66 + s];
    }
    __syncthreads();

    const int f  = sFlagL[rl];
    const int rk = sRank[rl];
    const int p  = (f == 0) ? (int)(sBase[0] + rk) : (Bsz - 1 - (int)(sBase[1] + rk));

    // single predicated X store (select flavor in registers, one 8B store)
    const float sc = useV ? rnfv : rnfi;
    const float x0 = useV ? afv.x : afi.x;
    const float x1 = useV ? afv.y : afi.y;
    const float x2 = useV ? afv.z : afi.z;
    const float x3 = useV ? afv.w : afi.w;
    ((uint2*)Xb)[p * 32 + c] = make_uint2(pack_bf16(x0 * sc, x1 * sc),
                                          pack_bf16(x2 * sc, x3 * sc));

    if (c == 0) {
        posArr[p]  = pos;
        origArr[p] = b;
        flagArr[p] = f;
        lAcc[p]    = 0.0f;
    }
}

// ---------------- main: BM=64, XCD-sliced, 4 blocks/CU, split prefetch ----------
// grid 1024 1-D: slice = blk&7 (XCD-keyed j-range), rowblk = blk>>3.
// 4 waves: each owns ALL 64 rows (afr[4][4]) and 16 of the slice's 64 col-tiles.
// A/B frag: [m|n=lane&15][k=quad*8+j]; C/D: col=lane&15, row=quad*4+reg.
//
// Proven structure (round-0): mid-iteration register prefetch of next tile's
// B-fragments (reload b0/b1 right after their last use, b2/b3 after theirs)
// keeps peak b-liveness at ~24 regs while covering L2 latency with the
// remaining MFMAs + exp block.  Round-1 lesson: removing this exposes the
// full L2 latency per iteration (117 µs, MfmaUtil 5.6%).  NO device-scope
// fences anywhere in this kernel (round-1's per-block __threadfence caused
// XCD-L2 writeback storms).
//
// Kept from round-1: unconditional per-phase rowsum (flavor predication moved
// to the once-per-phase reduce+atomic; at most ONE mixed-flavor block exists)
// and the 3-inst exp path: exp((S-1)/T) == exp2(S*K1 + K2) -> fma+exp+add.
__global__ __launch_bounds__(256, 4) void main_kernel(
    const unsigned short* __restrict__ Xb,
    const uint4* __restrict__ Yf0q, const uint4* __restrict__ Yf1q,
    const int* __restrict__ flagArr, float* __restrict__ lAcc)
{
    __shared__ uint4 sXf[1024];        // 16 KB: X fragment-ordered, rot2-swizzled
    __shared__ int sFlag[BM];
    __shared__ int sHas[2];

    const int t    = threadIdx.x;
    const int wave = t >> 6;
    const int lane = t & 63;
    const int quad = lane >> 4;
    const int mrow = lane & 15;
    const int slice = blockIdx.x & 7;
    const int p0    = (blockIdx.x >> 3) * BM;

    if (t < 2) sHas[t] = 0;
    __syncthreads();
    if (t < BM) {
        const int f = flagArr[p0 + t];
        sFlag[t] = f;
        atomicOr(&sHas[f], 1);
    }

    // stage X fragment-ordered with rot2 bank swizzle (conflict-free write+read)
    #pragma unroll
    for (int it = 0; it < 4; ++it) {
        const int i = t + it * 256;
        const int row = i >> 4, ch = i & 15;
        const uint4 val = ((const uint4*)Xb)[(p0 + row) * 16 + ch];
        const int blk16 = (row >> 4) * 4 + (ch >> 2);
        const int slot  = (ch & 3) * 16 + (row & 15);
        sXf[blk16 * 64 + ROT2(slot)] = val;
    }
    __syncthreads();

    // persistent A fragments (slot == lane identity => read at ROT2(lane))
    short8 afr[4][4];
    #pragma unroll
    for (int rt = 0; rt < 4; ++rt)
        #pragma unroll
        for (int kc = 0; kc < 4; ++kc)
            afr[rt][kc] = *(const short8*)&sXf[(rt * 4 + kc) * 64 + ROT2(lane)];

    const int g0 = slice * 64 + wave * 16;   // first of 16 col-tiles for this wave

    for (int phase = 0; phase < 2; ++phase) {
        if (!sHas[phase]) continue;          // flavor-pure blocks run one phase
        const uint4* __restrict__ yb = (phase ? Yf1q : Yf0q) + (size_t)g0 * 256 + lane;

        float rowsum[4][4] = {};             // unconditional per-phase exp-sums

        short8 b0 = *(const short8*)&yb[0];      // tile g, kc0
        short8 b1 = *(const short8*)&yb[64];     // kc1
        short8 b2 = *(const short8*)&yb[128];    // kc2
        short8 b3 = *(const short8*)&yb[192];    // kc3

        #pragma unroll 1
        for (int jt = 0; jt < 16; ++jt) {
            float4v acc[4] = {};
            #pragma unroll
            for (int rt = 0; rt < 4; ++rt)
                acc[rt] = __builtin_amdgcn_mfma_f32_16x16x32_bf16(afr[rt][0], b0, acc[rt], 0, 0, 0);
            #pragma unroll
            for (int rt = 0; rt < 4; ++rt)
                acc[rt] = __builtin_amdgcn_mfma_f32_16x16x32_bf16(afr[rt][1], b1, acc[rt], 0, 0, 0);
            if (jt < 15) {                       // prefetch next tile kc0/1 (~190cyc early)
                b0 = *(const short8*)&yb[256];
                b1 = *(const short8*)&yb[320];
            }
            #pragma unroll
            for (int rt = 0; rt < 4; ++rt)
                acc[rt] = __builtin_amdgcn_mfma_f32_16x16x32_bf16(afr[rt][2], b2, acc[rt], 0, 0, 0);
            #pragma unroll
            for (int rt = 0; rt < 4; ++rt)
                acc[rt] = __builtin_amdgcn_mfma_f32_16x16x32_bf16(afr[rt][3], b3, acc[rt], 0, 0, 0);
            if (jt < 15) {                       // prefetch next tile kc2/3
                b2 = *(const short8*)&yb[384];
                b3 = *(const short8*)&yb[448];
            }
            yb += 256;

            // fused exp-sum: exp((S-1)/T) == exp2(S*K1 + K2)  -> v_fma + v_exp + v_add
            #pragma unroll
            for (int rt = 0; rt < 4; ++rt)
                #pragma unroll
                for (int r = 0; r < 4; ++r)
                    rowsum[rt][r] += exp2f(fmaf(acc[rt][r], K1, K2));
        }

        // reduce over the 16 col-lanes of each quad, then flag-predicated atomic
        #pragma unroll
        for (int m = 1; m < 16; m <<= 1)
            #pragma unroll
            for (int rt = 0; rt < 4; ++rt)
                #pragma unroll
                for (int r = 0; r < 4; ++r)
                    rowsum[rt][r] += __shfl_xor(rowsum[rt][r], m);

        if (mrow == 0) {
            #pragma unroll
            for (int rt = 0; rt < 4; ++rt)
                #pragma unroll
                for (int r = 0; r < 4; ++r) {
                    const int row = rt * 16 + quad * 4 + r;
                    if (sFlag[row] == phase)
                        atomicAdd(&lAcc[p0 + row], rowsum[rt][r]);
                }
        }
    }
}

// ---------------- finish: loss in original row order ----------------
__global__ __launch_bounds__(256) void finish_kernel(
    const float* __restrict__ lAcc, const float* __restrict__ posArr,
    const int* __restrict__ origArr, float* __restrict__ out)
{
    const int p = blockIdx.x * 256 + threadIdx.x;
    out[origArr[p]] = logf(lAcc[p]) + INV_T - posArr[p] * INV_T;
}

// ---------------- launch ----------------
extern "C" void kernel_launch(void* const* d_in, const int* in_sizes, int n_in,
                              void* d_out, int out_size, void* d_ws, size_t ws_size,
                              hipStream_t stream)
{
    const float4* fv = (const float4*)d_in[0];
    const float4* fi = (const float4*)d_in[1];
    const float4* v  = (const float4*)d_in[2];
    const float4* vi = (const float4*)d_in[3];
    float* out = (float*)d_out;

    unsigned short* Xb  = (unsigned short*)d_ws;   // [B,128] bf16 row-major, compacted X
    unsigned short* Yf0 = Xb  + Bsz * Dd;          // [B*128] bf16, B-fragment-ordered v
    unsigned short* Yf1 = Yf0 + Bsz * Dd;          // [B*128] bf16, B-fragment-ordered vi
    float* posArr = (float*)(Yf1 + Bsz * Dd);      // [B] positive logit (compacted idx)
    float* lAcc   = posArr + Bsz;                  // [B] exp-sum accumulator
    int*  origArr = (int*)(lAcc + Bsz);            // [B] compacted -> original row
    int*  flagArr = origArr + Bsz;                 // [B] flavor per compacted row
    unsigned long long* cnt = (unsigned long long*)(flagArr + Bsz);

    hipLaunchKernelGGL(init_kernel, dim3(1), dim3(64), 0, stream, cnt);
    hipLaunchKernelGGL(prep_kernel, dim3(Bsz / 32), dim3(1024), 0, stream,
                       fv, fi, v, vi, (unsigned*)Xb, (uint2*)Yf0, (uint2*)Yf1,
                       posArr, origArr, flagArr, lAcc, cnt);
    hipLaunchKernelGGL(main_kernel, dim3((Bsz / BM) * NSLICE), dim3(256), 0, stream,
                       Xb, (const uint4*)Yf0, (const uint4*)Yf1, flagArr, lAcc);
    hipLaunchKernelGGL(finish_kernel, dim3(Bsz / 256), dim3(256), 0, stream,
                       lAcc, posArr, origArr, out);
}